// Round 14
// baseline (231.192 us; speedup 1.0000x reference)
//
#include <hip/hip_runtime.h>

#define HIDDEN 64
#define HALFD  32
#define VOCAB  64
#define BATCH  256
#define SEQLEN 2048
#define NCH    128            // chunks of 16

#define RLF(v, sl) __int_as_float(__builtin_amdgcn_readlane(__float_as_int(v), (sl)))
#define RLI(v, sl) __builtin_amdgcn_readlane((v), (sl))
#define GIX(j,m) (((j)==0?0:(j)==1?7:(j)==2?13:(j)==3?18:(j)==4?22:(j)==5?25:27) + (m) - (j) - 1)
#define OM(m) (((m)*((m)+1))>>1)

// ---------------------------------------------------------------------------
// Kernel 1: per-token vocab tables (unchanged).
//   ws[0    ..2047]  ks_voc [64][32]  (normalized hs)
//   ws[2048 ..4095]  ke_voc [64][32]  (normalized he)
//   ws[4096 ..6143]  vs_voc [64][32]  (raw hs)
//   ws[6144 ..8191]  ve_voc [64][32]  (raw he)
//   ws[8192 ..16383] Gs,Ge [2][64][64]
// ---------------------------------------------------------------------------
__global__ __launch_bounds__(64) void vocab_kernel(
    const float* __restrict__ embed, const float* __restrict__ W1, const float* __restrict__ b1,
    const float* __restrict__ W2, const float* __restrict__ b2,
    const float* __restrict__ ln_g, const float* __restrict__ ln_b,
    const float* __restrict__ Ws, const float* __restrict__ bs,
    const float* __restrict__ We, const float* __restrict__ be,
    float* __restrict__ ws)
{
    const int v = blockIdx.x;
    const int tid = threadIdx.x;

    __shared__ float e_s[64];
    __shared__ float a1_s[128];
    __shared__ float h_s[64];

    e_s[tid] = embed[v * 64 + tid];
    __syncthreads();

    float acc0 = b1[tid], acc1 = b1[tid + 64];
    #pragma unroll 8
    for (int m = 0; m < 64; ++m) {
        float ev = e_s[m];
        acc0 = fmaf(ev, W1[tid * 64 + m], acc0);
        acc1 = fmaf(ev, W1[(tid + 64) * 64 + m], acc1);
    }
    a1_s[tid]      = fmaxf(acc0, 0.0f);
    a1_s[tid + 64] = fmaxf(acc1, 0.0f);
    __syncthreads();

    float ff = b2[tid];
    #pragma unroll 8
    for (int m = 0; m < 128; ++m) ff = fmaf(a1_s[m], W2[tid * 128 + m], ff);
    float x = e_s[tid] + ff;

    float s = x, s2 = x * x;
    #pragma unroll
    for (int off = 32; off >= 1; off >>= 1) {
        s  += __shfl_xor(s,  off, 64);
        s2 += __shfl_xor(s2, off, 64);
    }
    float mu  = s * (1.0f / 64.0f);
    float var = s2 * (1.0f / 64.0f) - mu * mu;
    float hval = (x - mu) * rsqrtf(var + 1e-5f) * ln_g[tid] + ln_b[tid];
    h_s[tid] = hval;
    __syncthreads();

    const int j = tid & 31;
    const bool is_s = tid < 32;
    const float* W = is_s ? Ws : We;
    float acc = is_s ? bs[j] : be[j];
    #pragma unroll 8
    for (int m = 0; m < 64; ++m) acc = fmaf(h_s[m], W[j * 64 + m], acc);

    float n2 = acc * acc;
    #pragma unroll
    for (int off = 16; off >= 1; off >>= 1) n2 += __shfl_xor(n2, off, 64);
    float norm = sqrtf(n2);
    float kn = acc / fmaxf(norm, 1e-12f);

    const int base = v * 32 + j;
    if (is_s) { ws[base]        = kn; ws[4096 + base] = acc; }
    else      { ws[2048 + base] = kn; ws[6144 + base] = acc; }
}

// ---------------------------------------------------------------------------
// Kernel 1b: Gram tables (unchanged).
// ---------------------------------------------------------------------------
__global__ __launch_bounds__(256) void gram_kernel(float* __restrict__ ws)
{
    const int w = blockIdx.x;
    const int tid = threadIdx.x;
    __shared__ float k_s[2048];
    const float* kb = ws + w * 2048;
    for (int i = tid; i < 2048; i += 256) k_s[i] = kb[i];
    __syncthreads();
    const int a  = tid >> 2;
    const int b0 = (tid & 3) << 4;
    float* Gw = ws + 8192 + w * 4096 + a * 64;
    for (int bb = 0; bb < 16; ++bb) {
        const int bcol = b0 + bb;
        float acc = 0.f;
        #pragma unroll
        for (int m = 0; m < 32; ++m) acc = fmaf(k_s[a * 32 + m], k_s[bcol * 32 + m], acc);
        Gw[bcol] = acc;
    }
}

// chunk-8 W-pack build (verbatim R9 math; f folded, packed col-major OM)
static __device__ __forceinline__ void build_wpack(
    const int* tj, float fb, float invL, bool is_e, bool is_last, float* Wp,
    const float* __restrict__ Gg)
{
    float f[8];
    #pragma unroll
    for (int j = 0; j < 8; ++j) f[j] = is_e ? (fb + (float)j * invL) : 1.0f;
    if (is_last) f[7] = 0.0f;

    float g[28];
    #pragma unroll
    for (int j = 0; j < 7; ++j)
        #pragma unroll
        for (int m = j + 1; m < 8; ++m) g[GIX(j, m)] = Gg[tj[j] * 64 + tj[m]];

    #pragma unroll
    for (int m = 0; m < 8; ++m) {
        float col[8];
        col[m] = f[m];
        #pragma unroll
        for (int j = 6; j >= 0; --j) {
            if (j < m) {
                float acc = 0.0f;
                #pragma unroll
                for (int p = 1; p < 8; ++p)
                    if (p > j && p <= m) acc = fmaf(g[GIX(j, p)], col[p], acc);
                col[j] = -f[j] * acc;
            }
        }
        #pragma unroll
        for (int j = 0; j < 8; ++j)
            if (j <= m) Wp[OM(m) + j] = col[j];
    }
}

// apply a chunk-8 solve pack: s = W t  (36 independent FMAs, depth <= 4)
static __device__ __forceinline__ void apply_w8(
    const float* __restrict__ W, const float* __restrict__ t, float* __restrict__ s)
{
    s[7] = W[35] * t[7];
    s[6] = fmaf(W[27], t[6], W[34] * t[7]);
    s[5] = fmaf(W[20], t[5], W[26] * t[6]) + W[33] * t[7];
    s[4] = fmaf(W[14], t[4], W[19] * t[5]) + fmaf(W[25], t[6], W[32] * t[7]);
    s[3] = fmaf(W[9],  t[3], W[13] * t[4]) + fmaf(W[18], t[5], fmaf(W[24], t[6], W[31] * t[7]));
    s[2] = fmaf(W[5],  t[2], W[8]  * t[3]) + fmaf(W[12], t[4], W[17] * t[5]) + fmaf(W[23], t[6], W[30] * t[7]);
    s[1] = fmaf(W[2],  t[1], W[4]  * t[2]) + fmaf(W[7],  t[3], W[11] * t[4]) + fmaf(W[16], t[5], fmaf(W[22], t[6], W[29] * t[7]));
    s[0] = fmaf(W[0],  t[0], W[1]  * t[1]) + fmaf(W[3],  t[2], W[6]  * t[3]) + fmaf(W[10], t[4], W[15] * t[5]) + fmaf(W[21], t[6], W[28] * t[7]);
}

struct Chunk16 {
    int   tokv;        // lane-vector: tok[c*16 + (lane&15)] (bpermute index)
    int   tk[16];      // uniform tokens (SGPR via v_readlane)
    float grow[16];    // G[tok_j][lane] (VMEM-prefetched)
};

// ---------------------------------------------------------------------------
// Kernel 2: chunk-16 Gram-space backward sweep, hierarchical 2x chunk-8
// composition (R13 post-mortem: per-chunk fixed costs dominate; halve the
// serial chunk count). Pack per chunk-16 = [W_a(36) | W_b(36) | U_ab(64)]:
//   s_b = W_b t_b ;  s_a = W_a (t_a - U_ab s_b)   (exact block algebra)
// ONE bpermute per chunk-16 (lanes 0..15 carry t). End-of-body braw issue
// (R13 fix). Tokens/G-rows on VMEM, W on uniform LDS broadcast reads.
// ---------------------------------------------------------------------------
__global__ __launch_bounds__(128) void scan_kernel(
    const int* __restrict__ seq, const float* __restrict__ ws,
    const float* __restrict__ Wrp, const float* __restrict__ brp,
    const float* __restrict__ Wo, const float* __restrict__ bo,
    float* __restrict__ out)
{
    const int b    = blockIdx.x;
    const int tid  = threadIdx.x;        // 0..127
    const int w    = tid >> 6;           // wave: 0 = s-branch, 1 = e-branch
    const int lane = tid & 63;
    const int l15  = lane & 15;
    const bool is_e = (w == 1);

    __shared__ __align__(16) float4 Wt4[34][2][NCH];  // 136 KB, transposed
    __shared__ __align__(16) int    toklds[SEQLEN];   // 8 KB (prologue only)
    __shared__ float wacc_s[2][64];
    __shared__ float r_s[64];
    __shared__ float t1_s[64];

    const float* Gg = ws + 8192 + w * 4096;
    const int*   sq = seq + b * SEQLEN;

    // ---- stage token sequence (for the W-build prologue) ----
    {
        const int4* sq4 = (const int4*)sq;
        int4* tl = (int4*)toklds;
        #pragma unroll
        for (int i = 0; i < 4; ++i) tl[tid + i * 128] = sq4[tid + i * 128];
    }
    __syncthreads();

    // ---- precompute packs: lanes parallel over chunk-16s (2 per lane) ----
    {
        const float invL = 1.0f / (float)SEQLEN;
        #pragma unroll
        for (int qq = 0; qq < 2; ++qq) {
            const int c = lane + (qq << 6);
            int tj[16];
            #pragma unroll
            for (int j = 0; j < 16; ++j) tj[j] = toklds[c * 16 + j];

            float Wp[36];
            // W_a: positions 16c+0..7
            build_wpack(tj, (float)(16 * c + 1) * invL, invL, is_e, false, Wp, Gg);
            #pragma unroll
            for (int i = 0; i < 9; ++i)
                Wt4[i][w][c] = make_float4(Wp[4*i], Wp[4*i+1], Wp[4*i+2], Wp[4*i+3]);
            // W_b: positions 16c+8..15 (query = pos 2047 => c==127 last)
            build_wpack(tj + 8, (float)(16 * c + 9) * invL, invL, is_e, c == NCH - 1, Wp, Gg);
            #pragma unroll
            for (int i = 0; i < 9; ++i)
                Wt4[9 + i][w][c] = make_float4(Wp[4*i], Wp[4*i+1], Wp[4*i+2], Wp[4*i+3]);
            // U_ab[j][m] = G[tok_j][tok_{m+8}], raw Gram entries
            #pragma unroll
            for (int i = 0; i < 16; ++i) {
                const int j = i >> 1, m0 = (i & 1) << 2;
                Wt4[18 + i][w][c] = make_float4(
                    Gg[tj[j] * 64 + tj[8 + m0]],     Gg[tj[j] * 64 + tj[8 + m0 + 1]],
                    Gg[tj[j] * 64 + tj[8 + m0 + 2]], Gg[tj[j] * 64 + tj[8 + m0 + 3]]);
            }
        }
    }
    __syncthreads();

    // ---- serial backward sweep over 128 chunk-16s ----
    Chunk16 A, B;
    float u, waccv = 0.0f;

    A.tokv = sq[(NCH - 1) * 16 + l15];
    #pragma unroll
    for (int j = 0; j < 16; ++j) A.tk[j] = RLI(A.tokv, j);
    #pragma unroll
    for (int j = 0; j < 16; ++j) A.grow[j] = Gg[A.tk[j] * 64 + lane];
    B.tokv = sq[(NCH - 2) * 16 + l15];
    u = Gg[A.tk[15] * 64 + lane];              // query token = position 2047
    float braw = __shfl(u, A.tokv, 64);        // t-raw for chunk 127

    auto body = [&](Chunk16& cur, Chunk16& nxt, int c) {
        // ---- chain head: consume braw (issued end of previous body) ----
        float t[16];
        #pragma unroll
        for (int j = 0; j < 16; ++j) t[j] = RLF(braw, j);

        // ---- prefetch chunk c-1 into nxt (off-chain) ----
        const int cm2 = (c > 1) ? c - 2 : 0;
        #pragma unroll
        for (int j = 0; j < 16; ++j) nxt.tk[j] = RLI(nxt.tokv, j);
        #pragma unroll
        for (int j = 0; j < 16; ++j) nxt.grow[j] = Gg[nxt.tk[j] * 64 + lane];
        int tokv2 = sq[cm2 * 16 + l15];

        // ---- load this chunk's pack (uniform broadcast ds_read_b128) ----
        float Wa[36], Wb[36], U[64];
        #pragma unroll
        for (int i = 0; i < 9; ++i) {
            float4 v = Wt4[i][w][c];
            Wa[4*i] = v.x; Wa[4*i+1] = v.y; Wa[4*i+2] = v.z; Wa[4*i+3] = v.w;
        }
        #pragma unroll
        for (int i = 0; i < 9; ++i) {
            float4 v = Wt4[9 + i][w][c];
            Wb[4*i] = v.x; Wb[4*i+1] = v.y; Wb[4*i+2] = v.z; Wb[4*i+3] = v.w;
        }
        #pragma unroll
        for (int i = 0; i < 16; ++i) {
            float4 v = Wt4[18 + i][w][c];
            U[4*i] = v.x; U[4*i+1] = v.y; U[4*i+2] = v.z; U[4*i+3] = v.w;
        }

        // ---- block solve: s_b = Wb t_b ; s_a = Wa (t_a - U s_b) ----
        float sb[8], sa[8], ta[8];
        apply_w8(Wb, t + 8, sb);
        #pragma unroll
        for (int j = 0; j < 8; ++j) {
            const float* Uj = U + j * 8;
            float y0 = fmaf(Uj[0], sb[0], Uj[1] * sb[1]);
            float y1 = fmaf(Uj[2], sb[2], Uj[3] * sb[3]);
            float y2 = fmaf(Uj[4], sb[4], Uj[5] * sb[5]);
            float y3 = fmaf(Uj[6], sb[6], Uj[7] * sb[7]);
            ta[j] = t[j] - ((y0 + y1) + (y2 + y3));
        }
        apply_w8(Wa, ta, sa);

        // ---- u[a] -= sum_j s_j * G[tok_j][a] ----
        float d0 = fmaf(cur.grow[0],  sa[0], fmaf(cur.grow[1],  sa[1], fmaf(cur.grow[2],  sa[2], cur.grow[3]  * sa[3])));
        float d1 = fmaf(cur.grow[4],  sa[4], fmaf(cur.grow[5],  sa[5], fmaf(cur.grow[6],  sa[6], cur.grow[7]  * sa[7])));
        float d2 = fmaf(cur.grow[8],  sb[0], fmaf(cur.grow[9],  sb[1], fmaf(cur.grow[10], sb[2], cur.grow[11] * sb[3])));
        float d3 = fmaf(cur.grow[12], sb[4], fmaf(cur.grow[13], sb[5], fmaf(cur.grow[14], sb[6], cur.grow[15] * sb[7])));
        u -= ((d0 + d1) + (d2 + d3));

        // ---- issue next braw IMMEDIATELY (full body of slack) ----
        braw = __shfl(u, nxt.tokv, 64);

        // ---- wacc[tok_j] += s_j  (lane = token; off-chain) ----
        #pragma unroll
        for (int j = 0; j < 8; ++j) waccv += (lane == cur.tk[j])     ? sa[j] : 0.0f;
        #pragma unroll
        for (int j = 0; j < 8; ++j) waccv += (lane == cur.tk[8 + j]) ? sb[j] : 0.0f;

        cur.tokv = tokv2;   // retire cur; becomes chunk c-2's lane tokens
    };

    for (int c = NCH - 1; c >= 1; c -= 2) {
        body(A, B, c);
        body(B, A, c - 1);
    }

    wacc_s[w][lane] = waccv;
    __syncthreads();

    // r[w2][rho] = sum_tok wacc[w2][tok] * v[w2][tok][rho]  (v from global ws)
    if (tid < 64) {
        const int w2  = tid >> 5;
        const int rho = tid & 31;
        const float* vv = ws + 4096 + w2 * 2048;
        const float* wa = &wacc_s[w2][0];
        float acc = 0.0f;
        #pragma unroll 8
        for (int tok = 0; tok < 64; ++tok) acc = fmaf(wa[tok], vv[tok * 32 + rho], acc);
        r_s[tid] = acc;
    }
    __syncthreads();

    // out = (r @ Wrp.T + brp) @ Wo.T + bo
    if (tid < 64) {
        float acc = brp[tid];
        #pragma unroll 8
        for (int m = 0; m < 64; ++m) acc = fmaf(Wrp[tid * 64 + m], r_s[m], acc);
        t1_s[tid] = acc;
    }
    __syncthreads();
    if (tid < 64) {
        float acc = bo[tid];
        #pragma unroll 8
        for (int m = 0; m < 64; ++m) acc = fmaf(Wo[tid * 64 + m], t1_s[m], acc);
        out[b * 64 + tid] = acc;
    }
}

extern "C" void kernel_launch(void* const* d_in, const int* in_sizes, int n_in,
                              void* d_out, int out_size, void* d_ws, size_t ws_size,
                              hipStream_t stream)
{
    const int*   seq   = (const int*)  d_in[0];
    const float* embed = (const float*)d_in[1];
    const float* W1    = (const float*)d_in[2];
    const float* b1    = (const float*)d_in[3];
    const float* W2    = (const float*)d_in[4];
    const float* b2    = (const float*)d_in[5];
    const float* ln_g  = (const float*)d_in[6];
    const float* ln_b  = (const float*)d_in[7];
    const float* Ws    = (const float*)d_in[8];
    const float* bs    = (const float*)d_in[9];
    const float* We    = (const float*)d_in[10];
    const float* be    = (const float*)d_in[11];
    const float* Wrp   = (const float*)d_in[12];
    const float* brp   = (const float*)d_in[13];
    const float* Wo    = (const float*)d_in[14];
    const float* bo    = (const float*)d_in[15];
    float* ws  = (float*)d_ws;
    float* out = (float*)d_out;

    hipLaunchKernelGGL(vocab_kernel, dim3(VOCAB), dim3(64), 0, stream,
                       embed, W1, b1, W2, b2, ln_g, ln_b, Ws, bs, We, be, ws);
    hipLaunchKernelGGL(gram_kernel, dim3(2), dim3(256), 0, stream, ws);
    hipLaunchKernelGGL(scan_kernel, dim3(BATCH), dim3(128), 0, stream,
                       seq, ws, Wrp, brp, Wo, bo, out);
}

// Round 15
// 217.454 us; speedup vs baseline: 1.0632x; 1.0632x over previous
//
#include <hip/hip_runtime.h>

#define HIDDEN 64
#define HALFD  32
#define VOCAB  64
#define BATCH  256
#define SEQLEN 2048

#define RLF(v, sl) __int_as_float(__builtin_amdgcn_readlane(__float_as_int(v), (sl)))
#define RLI(v, sl) __builtin_amdgcn_readlane((v), (sl))
#define GIX(j,m) (((j)==0?0:(j)==1?7:(j)==2?13:(j)==3?18:(j)==4?22:(j)==5?25:27) + (m) - (j) - 1)
#define OM(m) (((m)*((m)+1))>>1)

// ---------------------------------------------------------------------------
// Kernel 1: per-token vocab tables (unchanged).
//   ws[0    ..2047]  ks_voc [64][32]  (normalized hs)
//   ws[2048 ..4095]  ke_voc [64][32]  (normalized he)
//   ws[4096 ..6143]  vs_voc [64][32]  (raw hs)
//   ws[6144 ..8191]  ve_voc [64][32]  (raw he)
//   ws[8192 ..16383] Gs,Ge [2][64][64]
// ---------------------------------------------------------------------------
__global__ __launch_bounds__(64) void vocab_kernel(
    const float* __restrict__ embed, const float* __restrict__ W1, const float* __restrict__ b1,
    const float* __restrict__ W2, const float* __restrict__ b2,
    const float* __restrict__ ln_g, const float* __restrict__ ln_b,
    const float* __restrict__ Ws, const float* __restrict__ bs,
    const float* __restrict__ We, const float* __restrict__ be,
    float* __restrict__ ws)
{
    const int v = blockIdx.x;
    const int tid = threadIdx.x;

    __shared__ float e_s[64];
    __shared__ float a1_s[128];
    __shared__ float h_s[64];

    e_s[tid] = embed[v * 64 + tid];
    __syncthreads();

    float acc0 = b1[tid], acc1 = b1[tid + 64];
    #pragma unroll 8
    for (int m = 0; m < 64; ++m) {
        float ev = e_s[m];
        acc0 = fmaf(ev, W1[tid * 64 + m], acc0);
        acc1 = fmaf(ev, W1[(tid + 64) * 64 + m], acc1);
    }
    a1_s[tid]      = fmaxf(acc0, 0.0f);
    a1_s[tid + 64] = fmaxf(acc1, 0.0f);
    __syncthreads();

    float ff = b2[tid];
    #pragma unroll 8
    for (int m = 0; m < 128; ++m) ff = fmaf(a1_s[m], W2[tid * 128 + m], ff);
    float x = e_s[tid] + ff;

    float s = x, s2 = x * x;
    #pragma unroll
    for (int off = 32; off >= 1; off >>= 1) {
        s  += __shfl_xor(s,  off, 64);
        s2 += __shfl_xor(s2, off, 64);
    }
    float mu  = s * (1.0f / 64.0f);
    float var = s2 * (1.0f / 64.0f) - mu * mu;
    float hval = (x - mu) * rsqrtf(var + 1e-5f) * ln_g[tid] + ln_b[tid];
    h_s[tid] = hval;
    __syncthreads();

    const int j = tid & 31;
    const bool is_s = tid < 32;
    const float* W = is_s ? Ws : We;
    float acc = is_s ? bs[j] : be[j];
    #pragma unroll 8
    for (int m = 0; m < 64; ++m) acc = fmaf(h_s[m], W[j * 64 + m], acc);

    float n2 = acc * acc;
    #pragma unroll
    for (int off = 16; off >= 1; off >>= 1) n2 += __shfl_xor(n2, off, 64);
    float norm = sqrtf(n2);
    float kn = acc / fmaxf(norm, 1e-12f);

    const int base = v * 32 + j;
    if (is_s) { ws[base]        = kn; ws[4096 + base] = acc; }
    else      { ws[2048 + base] = kn; ws[6144 + base] = acc; }
}

// ---------------------------------------------------------------------------
// Kernel 1b: Gram tables (unchanged).
// ---------------------------------------------------------------------------
__global__ __launch_bounds__(256) void gram_kernel(float* __restrict__ ws)
{
    const int w = blockIdx.x;
    const int tid = threadIdx.x;
    __shared__ float k_s[2048];
    const float* kb = ws + w * 2048;
    for (int i = tid; i < 2048; i += 256) k_s[i] = kb[i];
    __syncthreads();
    const int a  = tid >> 2;
    const int b0 = (tid & 3) << 4;
    float* Gw = ws + 8192 + w * 4096 + a * 64;
    for (int bb = 0; bb < 16; ++bb) {
        const int bcol = b0 + bb;
        float acc = 0.f;
        #pragma unroll
        for (int m = 0; m < 32; ++m) acc = fmaf(k_s[a * 32 + m], k_s[bcol * 32 + m], acc);
        Gw[bcol] = acc;
    }
}

// shared W-build routine (verbatim R9 math)
static __device__ __forceinline__ void build_wpack(
    const int* tj, float fb, float invL, bool is_e, bool is_last, float* Wp,
    const float* __restrict__ Gg)
{
    float f[8];
    #pragma unroll
    for (int j = 0; j < 8; ++j) f[j] = is_e ? (fb + (float)j * invL) : 1.0f;
    if (is_last) f[7] = 0.0f;     // position 2047 is the query, not a write

    float g[28];
    #pragma unroll
    for (int j = 0; j < 7; ++j)
        #pragma unroll
        for (int m = j + 1; m < 8; ++m) g[GIX(j, m)] = Gg[tj[j] * 64 + tj[m]];

    #pragma unroll
    for (int m = 0; m < 8; ++m) {
        float col[8];
        col[m] = f[m];
        #pragma unroll
        for (int j = 6; j >= 0; --j) {
            if (j < m) {
                float acc = 0.0f;
                #pragma unroll
                for (int p = 1; p < 8; ++p)
                    if (p > j && p <= m) acc = fmaf(g[GIX(j, p)], col[p], acc);
                col[j] = -f[j] * acc;
            }
        }
        #pragma unroll
        for (int j = 0; j < 8; ++j)
            if (j <= m) Wp[OM(m) + j] = col[j];
    }
}

struct Chunk {
    int   tokv;      // lane-vector: tok[c*8 + (lane&7)]  (bpermute index; VGPR)
    int   tk[8];     // uniform tokens of this chunk (SGPR via v_readlane)
    float grow[8];   // G[tok_j][lane]  (VMEM-prefetched)
    float W[36];     // packed upper-tri solve matrix (uniform LDS broadcast)
};

// ---------------------------------------------------------------------------
// Kernel 2: R13 champion with ONE change (R14 post-mortem): the next-chunk
// prefetch is moved from the body HEAD to the body TAIL, after the braw
// issue, with a 3-deep token pipeline (tvQ). DS completes in-order, so braw
// (issued first in the tail) is waited at the next head with the 9 W reads
// still outstanding; ~200+ cyc of independent prefetch issue now sits
// between braw issue and consumption, hiding the ds_bpermute latency that
// R13 exposed (~70-100 cyc/chunk).
// ---------------------------------------------------------------------------
__global__ __launch_bounds__(128) void scan_kernel(
    const int* __restrict__ seq, const float* __restrict__ ws,
    const float* __restrict__ Wrp, const float* __restrict__ brp,
    const float* __restrict__ Wo, const float* __restrict__ bo,
    float* __restrict__ out)
{
    const int b    = blockIdx.x;
    const int tid  = threadIdx.x;        // 0..127
    const int w    = tid >> 6;           // wave: 0 = s-branch, 1 = e-branch
    const int lane = tid & 63;
    const int l7   = lane & 7;
    const bool is_e = (w == 1);

    __shared__ __align__(16) float4 Wt4[9][2][256];   // 72 KB, transposed
    __shared__ __align__(16) int    toklds[SEQLEN];   // 8 KB (prologue only)
    __shared__ float wacc_s[2][64];
    __shared__ float r_s[64];
    __shared__ float t1_s[64];

    const float* Gg = ws + 8192 + w * 4096;
    const int*   sq = seq + b * SEQLEN;

    // ---- stage token sequence (for the W-build prologue) ----
    {
        const int4* sq4 = (const int4*)sq;
        int4* tl = (int4*)toklds;
        #pragma unroll
        for (int i = 0; i < 4; ++i) tl[tid + i * 128] = sq4[tid + i * 128];
    }
    __syncthreads();

    // ---- precompute W packs: lanes parallel over chunks (4 per lane) ----
    {
        const float invL = 1.0f / (float)SEQLEN;
        #pragma unroll
        for (int qq = 0; qq < 4; ++qq) {
            const int c = lane + (qq << 6);
            int tj[8];
            #pragma unroll
            for (int j = 0; j < 8; ++j) tj[j] = toklds[c * 8 + j];
            float Wp[36];
            build_wpack(tj, (float)(8 * c + 1) * invL, invL, is_e, c == 255, Wp, Gg);
            #pragma unroll
            for (int i = 0; i < 9; ++i)
                Wt4[i][w][c] = make_float4(Wp[4*i], Wp[4*i+1], Wp[4*i+2], Wp[4*i+3]);
        }
    }
    __syncthreads();

    // ---- serial backward sweep ----
    Chunk A, B;
    float u, waccv = 0.0f;

    // prologue: chunks 255 AND 254 fully; token pipeline 3 deep (tvQ = 253)
    A.tokv = sq[2040 + l7];
    #pragma unroll
    for (int j = 0; j < 8; ++j) A.tk[j] = RLI(A.tokv, j);
    #pragma unroll
    for (int j = 0; j < 8; ++j) A.grow[j] = Gg[A.tk[j] * 64 + lane];
    #pragma unroll
    for (int i = 0; i < 9; ++i) {
        float4 v = Wt4[i][w][255];
        A.W[4*i] = v.x; A.W[4*i+1] = v.y; A.W[4*i+2] = v.z; A.W[4*i+3] = v.w;
    }
    B.tokv = sq[2032 + l7];
    #pragma unroll
    for (int j = 0; j < 8; ++j) B.tk[j] = RLI(B.tokv, j);
    #pragma unroll
    for (int j = 0; j < 8; ++j) B.grow[j] = Gg[B.tk[j] * 64 + lane];
    #pragma unroll
    for (int i = 0; i < 9; ++i) {
        float4 v = Wt4[i][w][254];
        B.W[4*i] = v.x; B.W[4*i+1] = v.y; B.W[4*i+2] = v.z; B.W[4*i+3] = v.w;
    }
    int tvQ = sq[2024 + l7];                   // chunk 253 lane tokens

    u = Gg[A.tk[7] * 64 + lane];               // query token = position 2047
    float braw = __shfl(u, A.tokv, 64);        // t-raw for chunk 255

    auto body = [&](Chunk& cur, Chunk& nxt, int c) {
        // ---- chain head: consume braw (issued end of previous body; the
        //      prefetch ds_reads issued after it are still outstanding) ----
        float t0 = RLF(braw, 0), t1 = RLF(braw, 1), t2 = RLF(braw, 2), t3 = RLF(braw, 3);
        float t4 = RLF(braw, 4), t5 = RLF(braw, 5), t6 = RLF(braw, 6), t7 = RLF(braw, 7);

        // ---- s = W t  (36 independent FMAs, depth <= 4) ----
        const float* W = cur.W;
        float s7 = W[35] * t7;
        float s6 = fmaf(W[27], t6, W[34] * t7);
        float s5 = fmaf(W[20], t5, W[26] * t6) + W[33] * t7;
        float s4 = fmaf(W[14], t4, W[19] * t5) + fmaf(W[25], t6, W[32] * t7);
        float s3 = fmaf(W[9],  t3, W[13] * t4) + fmaf(W[18], t5, fmaf(W[24], t6, W[31] * t7));
        float s2 = fmaf(W[5],  t2, W[8]  * t3) + fmaf(W[12], t4, W[17] * t5) + fmaf(W[23], t6, W[30] * t7);
        float s1 = fmaf(W[2],  t1, W[4]  * t2) + fmaf(W[7],  t3, W[11] * t4) + fmaf(W[16], t5, fmaf(W[22], t6, W[29] * t7));
        float s0 = fmaf(W[0],  t0, W[1]  * t1) + fmaf(W[3],  t2, W[6]  * t3) + fmaf(W[10], t4, W[15] * t5) + fmaf(W[21], t6, W[28] * t7);

        // ---- u[a] -= sum_j s_j * G[tok_j][a] ----
        float dA = fmaf(cur.grow[0], s0, fmaf(cur.grow[1], s1, fmaf(cur.grow[2], s2, cur.grow[3] * s3)));
        float dB = fmaf(cur.grow[4], s4, fmaf(cur.grow[5], s5, fmaf(cur.grow[6], s6, cur.grow[7] * s7)));
        u -= (dA + dB);

        // ---- issue next braw IMMEDIATELY after u finalizes ----
        braw = __shfl(u, nxt.tokv, 64);

        // ---- wacc[tok_j] += s_j  (uses cur.tk BEFORE the refill below) ----
        waccv += (lane == cur.tk[0]) ? s0 : 0.0f;
        waccv += (lane == cur.tk[1]) ? s1 : 0.0f;
        waccv += (lane == cur.tk[2]) ? s2 : 0.0f;
        waccv += (lane == cur.tk[3]) ? s3 : 0.0f;
        waccv += (lane == cur.tk[4]) ? s4 : 0.0f;
        waccv += (lane == cur.tk[5]) ? s5 : 0.0f;
        waccv += (lane == cur.tk[6]) ? s6 : 0.0f;
        waccv += (lane == cur.tk[7]) ? s7 : 0.0f;

        // ---- TAIL prefetch: refill retiring buffer with chunk c-2.
        //      Issued AFTER braw -> its 9 ds_reads queue behind braw; the
        //      slack here (~200 cyc of VALU/VMEM) covers bpermute latency. ----
        const int cm2 = (c > 1) ? c - 2 : 0;
        const int cm3 = (c > 2) ? c - 3 : 0;
        cur.tokv = tvQ;
        #pragma unroll
        for (int j = 0; j < 8; ++j) cur.tk[j] = RLI(tvQ, j);
        #pragma unroll
        for (int j = 0; j < 8; ++j) cur.grow[j] = Gg[cur.tk[j] * 64 + lane];
        #pragma unroll
        for (int i = 0; i < 9; ++i) {
            float4 v = Wt4[i][w][cm2];
            cur.W[4*i] = v.x; cur.W[4*i+1] = v.y; cur.W[4*i+2] = v.z; cur.W[4*i+3] = v.w;
        }
        tvQ = sq[cm3 * 8 + l7];                // chunk c-3 lane tokens (VMEM)
    };

    for (int c = 255; c >= 1; c -= 2) {
        body(A, B, c);
        body(B, A, c - 1);
    }

    wacc_s[w][lane] = waccv;
    __syncthreads();

    // r[w2][rho] = sum_tok wacc[w2][tok] * v[w2][tok][rho]  (v from global ws)
    if (tid < 64) {
        const int w2  = tid >> 5;
        const int rho = tid & 31;
        const float* vv = ws + 4096 + w2 * 2048;
        const float* wa = &wacc_s[w2][0];
        float acc = 0.0f;
        #pragma unroll 8
        for (int tok = 0; tok < 64; ++tok) acc = fmaf(wa[tok], vv[tok * 32 + rho], acc);
        r_s[tid] = acc;
    }
    __syncthreads();

    // out = (r @ Wrp.T + brp) @ Wo.T + bo
    if (tid < 64) {
        float acc = brp[tid];
        #pragma unroll 8
        for (int m = 0; m < 64; ++m) acc = fmaf(Wrp[tid * 64 + m], r_s[m], acc);
        t1_s[tid] = acc;
    }
    __syncthreads();
    if (tid < 64) {
        float acc = bo[tid];
        #pragma unroll 8
        for (int m = 0; m < 64; ++m) acc = fmaf(Wo[tid * 64 + m], t1_s[m], acc);
        out[b * 64 + tid] = acc;
    }
}

extern "C" void kernel_launch(void* const* d_in, const int* in_sizes, int n_in,
                              void* d_out, int out_size, void* d_ws, size_t ws_size,
                              hipStream_t stream)
{
    const int*   seq   = (const int*)  d_in[0];
    const float* embed = (const float*)d_in[1];
    const float* W1    = (const float*)d_in[2];
    const float* b1    = (const float*)d_in[3];
    const float* W2    = (const float*)d_in[4];
    const float* b2    = (const float*)d_in[5];
    const float* ln_g  = (const float*)d_in[6];
    const float* ln_b  = (const float*)d_in[7];
    const float* Ws    = (const float*)d_in[8];
    const float* bs    = (const float*)d_in[9];
    const float* We    = (const float*)d_in[10];
    const float* be    = (const float*)d_in[11];
    const float* Wrp   = (const float*)d_in[12];
    const float* brp   = (const float*)d_in[13];
    const float* Wo    = (const float*)d_in[14];
    const float* bo    = (const float*)d_in[15];
    float* ws  = (float*)d_ws;
    float* out = (float*)d_out;

    hipLaunchKernelGGL(vocab_kernel, dim3(VOCAB), dim3(64), 0, stream,
                       embed, W1, b1, W2, b2, ln_g, ln_b, Ws, bs, We, be, ws);
    hipLaunchKernelGGL(gram_kernel, dim3(2), dim3(256), 0, stream, ws);
    hipLaunchKernelGGL(scan_kernel, dim3(BATCH), dim3(128), 0, stream,
                       seq, ws, Wrp, brp, Wo, bo, out);
}

// Round 16
// 207.594 us; speedup vs baseline: 1.1137x; 1.0475x over previous
//
#include <hip/hip_runtime.h>

#define HIDDEN 64
#define HALFD  32
#define VOCAB  64
#define BATCH  256
#define SEQLEN 2048

#define RLF(v, sl) __int_as_float(__builtin_amdgcn_readlane(__float_as_int(v), (sl)))
#define RLI(v, sl) __builtin_amdgcn_readlane((v), (sl))
#define GIX(j,m) (((j)==0?0:(j)==1?7:(j)==2?13:(j)==3?18:(j)==4?22:(j)==5?25:27) + (m) - (j) - 1)
#define OM(m) (((m)*((m)+1))>>1)

// ---------------------------------------------------------------------------
// Kernel 1: per-token vocab tables (unchanged).
//   ws[0    ..2047]  ks_voc [64][32]  (normalized hs)
//   ws[2048 ..4095]  ke_voc [64][32]  (normalized he)
//   ws[4096 ..6143]  vs_voc [64][32]  (raw hs)
//   ws[6144 ..8191]  ve_voc [64][32]  (raw he)
//   ws[8192 ..16383] Gs,Ge [2][64][64]
// ---------------------------------------------------------------------------
__global__ __launch_bounds__(64) void vocab_kernel(
    const float* __restrict__ embed, const float* __restrict__ W1, const float* __restrict__ b1,
    const float* __restrict__ W2, const float* __restrict__ b2,
    const float* __restrict__ ln_g, const float* __restrict__ ln_b,
    const float* __restrict__ Ws, const float* __restrict__ bs,
    const float* __restrict__ We, const float* __restrict__ be,
    float* __restrict__ ws)
{
    const int v = blockIdx.x;
    const int tid = threadIdx.x;

    __shared__ float e_s[64];
    __shared__ float a1_s[128];
    __shared__ float h_s[64];

    e_s[tid] = embed[v * 64 + tid];
    __syncthreads();

    float acc0 = b1[tid], acc1 = b1[tid + 64];
    #pragma unroll 8
    for (int m = 0; m < 64; ++m) {
        float ev = e_s[m];
        acc0 = fmaf(ev, W1[tid * 64 + m], acc0);
        acc1 = fmaf(ev, W1[(tid + 64) * 64 + m], acc1);
    }
    a1_s[tid]      = fmaxf(acc0, 0.0f);
    a1_s[tid + 64] = fmaxf(acc1, 0.0f);
    __syncthreads();

    float ff = b2[tid];
    #pragma unroll 8
    for (int m = 0; m < 128; ++m) ff = fmaf(a1_s[m], W2[tid * 128 + m], ff);
    float x = e_s[tid] + ff;

    float s = x, s2 = x * x;
    #pragma unroll
    for (int off = 32; off >= 1; off >>= 1) {
        s  += __shfl_xor(s,  off, 64);
        s2 += __shfl_xor(s2, off, 64);
    }
    float mu  = s * (1.0f / 64.0f);
    float var = s2 * (1.0f / 64.0f) - mu * mu;
    float hval = (x - mu) * rsqrtf(var + 1e-5f) * ln_g[tid] + ln_b[tid];
    h_s[tid] = hval;
    __syncthreads();

    const int j = tid & 31;
    const bool is_s = tid < 32;
    const float* W = is_s ? Ws : We;
    float acc = is_s ? bs[j] : be[j];
    #pragma unroll 8
    for (int m = 0; m < 64; ++m) acc = fmaf(h_s[m], W[j * 64 + m], acc);

    float n2 = acc * acc;
    #pragma unroll
    for (int off = 16; off >= 1; off >>= 1) n2 += __shfl_xor(n2, off, 64);
    float norm = sqrtf(n2);
    float kn = acc / fmaxf(norm, 1e-12f);

    const int base = v * 32 + j;
    if (is_s) { ws[base]        = kn; ws[4096 + base] = acc; }
    else      { ws[2048 + base] = kn; ws[6144 + base] = acc; }
}

// ---------------------------------------------------------------------------
// Kernel 1b: Gram tables (unchanged).
// ---------------------------------------------------------------------------
__global__ __launch_bounds__(256) void gram_kernel(float* __restrict__ ws)
{
    const int w = blockIdx.x;
    const int tid = threadIdx.x;
    __shared__ float k_s[2048];
    const float* kb = ws + w * 2048;
    for (int i = tid; i < 2048; i += 256) k_s[i] = kb[i];
    __syncthreads();
    const int a  = tid >> 2;
    const int b0 = (tid & 3) << 4;
    float* Gw = ws + 8192 + w * 4096 + a * 64;
    for (int bb = 0; bb < 16; ++bb) {
        const int bcol = b0 + bb;
        float acc = 0.f;
        #pragma unroll
        for (int m = 0; m < 32; ++m) acc = fmaf(k_s[a * 32 + m], k_s[bcol * 32 + m], acc);
        Gw[bcol] = acc;
    }
}

// shared W-build routine (verbatim R9 math)
static __device__ __forceinline__ void build_wpack(
    const int* tj, float fb, float invL, bool is_e, bool is_last, float* Wp,
    const float* __restrict__ Gg)
{
    float f[8];
    #pragma unroll
    for (int j = 0; j < 8; ++j) f[j] = is_e ? (fb + (float)j * invL) : 1.0f;
    if (is_last) f[7] = 0.0f;     // position 2047 is the query, not a write

    float g[28];
    #pragma unroll
    for (int j = 0; j < 7; ++j)
        #pragma unroll
        for (int m = j + 1; m < 8; ++m) g[GIX(j, m)] = Gg[tj[j] * 64 + tj[m]];

    #pragma unroll
    for (int m = 0; m < 8; ++m) {
        float col[8];
        col[m] = f[m];
        #pragma unroll
        for (int j = 6; j >= 0; --j) {
            if (j < m) {
                float acc = 0.0f;
                #pragma unroll
                for (int p = 1; p < 8; ++p)
                    if (p > j && p <= m) acc = fmaf(g[GIX(j, p)], col[p], acc);
                col[j] = -f[j] * acc;
            }
        }
        #pragma unroll
        for (int j = 0; j < 8; ++j)
            if (j <= m) Wp[OM(m) + j] = col[j];
    }
}

struct Chunk {
    int   tokv;      // lane-vector: tok[c*8 + (lane&7)] (source for tk extraction)
    int   tk[8];     // uniform tokens of this chunk (SGPR via v_readlane)
    float grow[8];   // G[tok_j][lane]  (VMEM-prefetched)
    float W[36];     // packed upper-tri solve matrix (uniform LDS broadcast)
};

// ---------------------------------------------------------------------------
// Kernel 2: R13 champion with ONE change (R15 post-mortem): the ds_bpermute
// is ELIMINATED. t_j = u[tok_j] with tok_j in an SGPR is exactly
// v_readlane_b32(u, s_tk) — a VALU cross-lane read, the same mechanism used
// for g extraction since R7. The loop now has ZERO chain-coupled DS ops;
// the only DS left is the 9 uniform W reads, prefetched one full body ahead
// (R13's proven placement — R15 showed moving them costs their slack).
// Chain/chunk: u-write->readlane hazard + 8 readlanes + depth-4 solve +
// depth-3 u-update. Everything else verbatim R13.
// ---------------------------------------------------------------------------
__global__ __launch_bounds__(128) void scan_kernel(
    const int* __restrict__ seq, const float* __restrict__ ws,
    const float* __restrict__ Wrp, const float* __restrict__ brp,
    const float* __restrict__ Wo, const float* __restrict__ bo,
    float* __restrict__ out)
{
    const int b    = blockIdx.x;
    const int tid  = threadIdx.x;        // 0..127
    const int w    = tid >> 6;           // wave: 0 = s-branch, 1 = e-branch
    const int lane = tid & 63;
    const int l7   = lane & 7;
    const bool is_e = (w == 1);

    __shared__ __align__(16) float4 Wt4[9][2][256];   // 72 KB, transposed
    __shared__ __align__(16) int    toklds[SEQLEN];   // 8 KB (prologue only)
    __shared__ float wacc_s[2][64];
    __shared__ float r_s[64];
    __shared__ float t1_s[64];

    const float* Gg = ws + 8192 + w * 4096;
    const int*   sq = seq + b * SEQLEN;

    // ---- stage token sequence (for the W-build prologue) ----
    {
        const int4* sq4 = (const int4*)sq;
        int4* tl = (int4*)toklds;
        #pragma unroll
        for (int i = 0; i < 4; ++i) tl[tid + i * 128] = sq4[tid + i * 128];
    }
    __syncthreads();

    // ---- precompute W packs: lanes parallel over chunks (4 per lane) ----
    {
        const float invL = 1.0f / (float)SEQLEN;
        #pragma unroll
        for (int qq = 0; qq < 4; ++qq) {
            const int c = lane + (qq << 6);
            int tj[8];
            #pragma unroll
            for (int j = 0; j < 8; ++j) tj[j] = toklds[c * 8 + j];
            float Wp[36];
            build_wpack(tj, (float)(8 * c + 1) * invL, invL, is_e, c == 255, Wp, Gg);
            #pragma unroll
            for (int i = 0; i < 9; ++i)
                Wt4[i][w][c] = make_float4(Wp[4*i], Wp[4*i+1], Wp[4*i+2], Wp[4*i+3]);
        }
    }
    __syncthreads();

    // ---- serial backward sweep ----
    Chunk A, B;
    float u, waccv = 0.0f;

    // prologue: chunk 255 fully, chunk 254 lane-tokens
    A.tokv = sq[2040 + l7];                    // VMEM per-lane
    #pragma unroll
    for (int j = 0; j < 8; ++j) A.tk[j] = RLI(A.tokv, j);
    #pragma unroll
    for (int j = 0; j < 8; ++j) A.grow[j] = Gg[A.tk[j] * 64 + lane];
    #pragma unroll
    for (int i = 0; i < 9; ++i) {
        float4 v = Wt4[i][w][255];
        A.W[4*i] = v.x; A.W[4*i+1] = v.y; A.W[4*i+2] = v.z; A.W[4*i+3] = v.w;
    }
    B.tokv = sq[2032 + l7];
    u = Gg[A.tk[7] * 64 + lane];               // query token = position 2047

    auto body = [&](Chunk& cur, Chunk& nxt, int c) {
        // ---- chain head: t_j = u[tok_j] via v_readlane (SGPR index, VALU) ----
        float t0 = RLF(u, cur.tk[0]), t1 = RLF(u, cur.tk[1]);
        float t2 = RLF(u, cur.tk[2]), t3 = RLF(u, cur.tk[3]);
        float t4 = RLF(u, cur.tk[4]), t5 = RLF(u, cur.tk[5]);
        float t6 = RLF(u, cur.tk[6]), t7 = RLF(u, cur.tk[7]);

        // ---- prefetch chunk c-1 into nxt (off-chain; R13 placement) ----
        const int cm1 = (c > 0) ? c - 1 : 0;
        const int cm2 = (c > 1) ? c - 2 : 0;
        #pragma unroll
        for (int j = 0; j < 8; ++j) nxt.tk[j] = RLI(nxt.tokv, j);
        #pragma unroll
        for (int j = 0; j < 8; ++j) nxt.grow[j] = Gg[nxt.tk[j] * 64 + lane];
        #pragma unroll
        for (int i = 0; i < 9; ++i) {
            float4 v = Wt4[i][w][cm1];
            nxt.W[4*i] = v.x; nxt.W[4*i+1] = v.y; nxt.W[4*i+2] = v.z; nxt.W[4*i+3] = v.w;
        }
        int tokv2 = sq[cm2 * 8 + l7];          // VMEM per-lane (chunk c-2)

        // ---- s = W t  (36 independent FMAs, depth <= 4) ----
        const float* W = cur.W;
        float s7 = W[35] * t7;
        float s6 = fmaf(W[27], t6, W[34] * t7);
        float s5 = fmaf(W[20], t5, W[26] * t6) + W[33] * t7;
        float s4 = fmaf(W[14], t4, W[19] * t5) + fmaf(W[25], t6, W[32] * t7);
        float s3 = fmaf(W[9],  t3, W[13] * t4) + fmaf(W[18], t5, fmaf(W[24], t6, W[31] * t7));
        float s2 = fmaf(W[5],  t2, W[8]  * t3) + fmaf(W[12], t4, W[17] * t5) + fmaf(W[23], t6, W[30] * t7);
        float s1 = fmaf(W[2],  t1, W[4]  * t2) + fmaf(W[7],  t3, W[11] * t4) + fmaf(W[16], t5, fmaf(W[22], t6, W[29] * t7));
        float s0 = fmaf(W[0],  t0, W[1]  * t1) + fmaf(W[3],  t2, W[6]  * t3) + fmaf(W[10], t4, W[15] * t5) + fmaf(W[21], t6, W[28] * t7);

        // ---- u[a] -= sum_j s_j * G[tok_j][a] ----
        float dA = fmaf(cur.grow[0], s0, fmaf(cur.grow[1], s1, fmaf(cur.grow[2], s2, cur.grow[3] * s3)));
        float dB = fmaf(cur.grow[4], s4, fmaf(cur.grow[5], s5, fmaf(cur.grow[6], s6, cur.grow[7] * s7)));
        u -= (dA + dB);

        // ---- wacc[tok_j] += s_j  (lane = token; covers the u->readlane gap) ----
        waccv += (lane == cur.tk[0]) ? s0 : 0.0f;
        waccv += (lane == cur.tk[1]) ? s1 : 0.0f;
        waccv += (lane == cur.tk[2]) ? s2 : 0.0f;
        waccv += (lane == cur.tk[3]) ? s3 : 0.0f;
        waccv += (lane == cur.tk[4]) ? s4 : 0.0f;
        waccv += (lane == cur.tk[5]) ? s5 : 0.0f;
        waccv += (lane == cur.tk[6]) ? s6 : 0.0f;
        waccv += (lane == cur.tk[7]) ? s7 : 0.0f;

        cur.tokv = tokv2;   // retire cur; becomes chunk c-2's lane tokens
    };

    for (int c = 255; c >= 1; c -= 2) {
        body(A, B, c);
        body(B, A, c - 1);
    }

    wacc_s[w][lane] = waccv;
    __syncthreads();

    // r[w2][rho] = sum_tok wacc[w2][tok] * v[w2][tok][rho]  (v from global ws)
    if (tid < 64) {
        const int w2  = tid >> 5;
        const int rho = tid & 31;
        const float* vv = ws + 4096 + w2 * 2048;
        const float* wa = &wacc_s[w2][0];
        float acc = 0.0f;
        #pragma unroll 8
        for (int tok = 0; tok < 64; ++tok) acc = fmaf(wa[tok], vv[tok * 32 + rho], acc);
        r_s[tid] = acc;
    }
    __syncthreads();

    // out = (r @ Wrp.T + brp) @ Wo.T + bo
    if (tid < 64) {
        float acc = brp[tid];
        #pragma unroll 8
        for (int m = 0; m < 64; ++m) acc = fmaf(Wrp[tid * 64 + m], r_s[m], acc);
        t1_s[tid] = acc;
    }
    __syncthreads();
    if (tid < 64) {
        float acc = bo[tid];
        #pragma unroll 8
        for (int m = 0; m < 64; ++m) acc = fmaf(Wo[tid * 64 + m], t1_s[m], acc);
        out[b * 64 + tid] = acc;
    }
}

extern "C" void kernel_launch(void* const* d_in, const int* in_sizes, int n_in,
                              void* d_out, int out_size, void* d_ws, size_t ws_size,
                              hipStream_t stream)
{
    const int*   seq   = (const int*)  d_in[0];
    const float* embed = (const float*)d_in[1];
    const float* W1    = (const float*)d_in[2];
    const float* b1    = (const float*)d_in[3];
    const float* W2    = (const float*)d_in[4];
    const float* b2    = (const float*)d_in[5];
    const float* ln_g  = (const float*)d_in[6];
    const float* ln_b  = (const float*)d_in[7];
    const float* Ws    = (const float*)d_in[8];
    const float* bs    = (const float*)d_in[9];
    const float* We    = (const float*)d_in[10];
    const float* be    = (const float*)d_in[11];
    const float* Wrp   = (const float*)d_in[12];
    const float* brp   = (const float*)d_in[13];
    const float* Wo    = (const float*)d_in[14];
    const float* bo    = (const float*)d_in[15];
    float* ws  = (float*)d_ws;
    float* out = (float*)d_out;

    hipLaunchKernelGGL(vocab_kernel, dim3(VOCAB), dim3(64), 0, stream,
                       embed, W1, b1, W2, b2, ln_g, ln_b, Ws, bs, We, be, ws);
    hipLaunchKernelGGL(gram_kernel, dim3(2), dim3(256), 0, stream, ws);
    hipLaunchKernelGGL(scan_kernel, dim3(BATCH), dim3(128), 0, stream,
                       seq, ws, Wrp, brp, Wo, bo, out);
}

// Round 17
// 200.184 us; speedup vs baseline: 1.1549x; 1.0370x over previous
//
#include <hip/hip_runtime.h>

#define HIDDEN 64
#define HALFD  32
#define VOCAB  64
#define BATCH  256
#define SEQLEN 2048

#define RLF(v, sl) __int_as_float(__builtin_amdgcn_readlane(__float_as_int(v), (sl)))
#define RLI(v, sl) __builtin_amdgcn_readlane((v), (sl))
#define GIX(j,m) (((j)==0?0:(j)==1?7:(j)==2?13:(j)==3?18:(j)==4?22:(j)==5?25:27) + (m) - (j) - 1)
#define OM(m) (((m)*((m)+1))>>1)

// ---------------------------------------------------------------------------
// Kernel 1: per-token vocab tables.
//   ws[0    ..2047]  ks_voc [64][32]  (normalized hs)
//   ws[2048 ..4095]  ke_voc [64][32]  (normalized he)
//   ws[4096 ..6143]  vs_voc [64][32]  (raw hs)
//   ws[6144 ..8191]  ve_voc [64][32]  (raw he)
//   ws[8192 ..16383] Gs,Ge [2][64][64]
// ---------------------------------------------------------------------------
__global__ __launch_bounds__(64) void vocab_kernel(
    const float* __restrict__ embed, const float* __restrict__ W1, const float* __restrict__ b1,
    const float* __restrict__ W2, const float* __restrict__ b2,
    const float* __restrict__ ln_g, const float* __restrict__ ln_b,
    const float* __restrict__ Ws, const float* __restrict__ bs,
    const float* __restrict__ We, const float* __restrict__ be,
    float* __restrict__ ws)
{
    const int v = blockIdx.x;
    const int tid = threadIdx.x;

    __shared__ float e_s[64];
    __shared__ float a1_s[128];
    __shared__ float h_s[64];

    e_s[tid] = embed[v * 64 + tid];
    __syncthreads();

    float acc0 = b1[tid], acc1 = b1[tid + 64];
    #pragma unroll 8
    for (int m = 0; m < 64; ++m) {
        float ev = e_s[m];
        acc0 = fmaf(ev, W1[tid * 64 + m], acc0);
        acc1 = fmaf(ev, W1[(tid + 64) * 64 + m], acc1);
    }
    a1_s[tid]      = fmaxf(acc0, 0.0f);
    a1_s[tid + 64] = fmaxf(acc1, 0.0f);
    __syncthreads();

    float ff = b2[tid];
    #pragma unroll 8
    for (int m = 0; m < 128; ++m) ff = fmaf(a1_s[m], W2[tid * 128 + m], ff);
    float x = e_s[tid] + ff;

    float s = x, s2 = x * x;
    #pragma unroll
    for (int off = 32; off >= 1; off >>= 1) {
        s  += __shfl_xor(s,  off, 64);
        s2 += __shfl_xor(s2, off, 64);
    }
    float mu  = s * (1.0f / 64.0f);
    float var = s2 * (1.0f / 64.0f) - mu * mu;
    float hval = (x - mu) * rsqrtf(var + 1e-5f) * ln_g[tid] + ln_b[tid];
    h_s[tid] = hval;
    __syncthreads();

    const int j = tid & 31;
    const bool is_s = tid < 32;
    const float* W = is_s ? Ws : We;
    float acc = is_s ? bs[j] : be[j];
    #pragma unroll 8
    for (int m = 0; m < 64; ++m) acc = fmaf(h_s[m], W[j * 64 + m], acc);

    float n2 = acc * acc;
    #pragma unroll
    for (int off = 16; off >= 1; off >>= 1) n2 += __shfl_xor(n2, off, 64);
    float norm = sqrtf(n2);
    float kn = acc / fmaxf(norm, 1e-12f);

    const int base = v * 32 + j;
    if (is_s) { ws[base]        = kn; ws[4096 + base] = acc; }
    else      { ws[2048 + base] = kn; ws[6144 + base] = acc; }
}

// ---------------------------------------------------------------------------
// Kernel 1b: Gram tables G_w[a][b] = k_w[a].k_w[b], [64][64] in ws.
// ---------------------------------------------------------------------------
__global__ __launch_bounds__(256) void gram_kernel(float* __restrict__ ws)
{
    const int w = blockIdx.x;
    const int tid = threadIdx.x;
    __shared__ float k_s[2048];
    const float* kb = ws + w * 2048;
    for (int i = tid; i < 2048; i += 256) k_s[i] = kb[i];
    __syncthreads();
    const int a  = tid >> 2;
    const int b0 = (tid & 3) << 4;
    float* Gw = ws + 8192 + w * 4096 + a * 64;
    for (int bb = 0; bb < 16; ++bb) {
        const int bcol = b0 + bb;
        float acc = 0.f;
        #pragma unroll
        for (int m = 0; m < 32; ++m) acc = fmaf(k_s[a * 32 + m], k_s[bcol * 32 + m], acc);
        Gw[bcol] = acc;
    }
}

// chunk-8 solve-matrix build: s = W t with f folded (verbatim R9 math)
static __device__ __forceinline__ void build_wpack(
    const int* tj, float fb, float invL, bool is_e, bool is_last, float* Wp,
    const float* __restrict__ Gg)
{
    float f[8];
    #pragma unroll
    for (int j = 0; j < 8; ++j) f[j] = is_e ? (fb + (float)j * invL) : 1.0f;
    if (is_last) f[7] = 0.0f;     // position 2047 is the query, not a write

    float g[28];
    #pragma unroll
    for (int j = 0; j < 7; ++j)
        #pragma unroll
        for (int m = j + 1; m < 8; ++m) g[GIX(j, m)] = Gg[tj[j] * 64 + tj[m]];

    #pragma unroll
    for (int m = 0; m < 8; ++m) {
        float col[8];
        col[m] = f[m];
        #pragma unroll
        for (int j = 6; j >= 0; --j) {
            if (j < m) {
                float acc = 0.0f;
                #pragma unroll
                for (int p = 1; p < 8; ++p)
                    if (p > j && p <= m) acc = fmaf(g[GIX(j, p)], col[p], acc);
                col[j] = -f[j] * acc;
            }
        }
        #pragma unroll
        for (int j = 0; j < 8; ++j)
            if (j <= m) Wp[OM(m) + j] = col[j];
    }
}

struct Chunk {
    int   tokv;      // lane-vector: tok[c*8 + (lane&7)]  (bpermute index; VGPR)
    int   tk[8];     // uniform tokens of this chunk (SGPR via v_readlane)
    float grow[8];   // G[tok_j][lane]  (VMEM-prefetched)
    float W[36];     // packed upper-tri solve matrix (uniform LDS broadcast)
};

// ---------------------------------------------------------------------------
// Kernel 2 (CHAMPION, R13): Gram-space backward adjoint sweep in chunks of 8.
// State per wave: u[a] = k_a . q (one float/lane, lane = vocab token) and
// wacc[a]. Per chunk: ONE ds_bpermute gathers t_j = u[tok_j] (lane j holds
// its own index; issued END of previous body -> a full body of slack); 8
// t-readlane broadcasts; s = W t (W = precomputed per-chunk solve matrix,
// 36 FMAs depth<=4, LDS broadcast reads prefetched one body ahead); 9-FMA
// u-update; wacc compare-selects. G rows on VMEM, tokens on per-lane VMEM.
// Measured floor of this structure: ~1022 cyc/chunk (~560 issue at ~54%
// single-wave ILP + chain/W-wait residue). Surgical variants R14-R16
// (chunk-16, tail prefetch, readlane-for-bpermute) all regressed.
// ---------------------------------------------------------------------------
__global__ __launch_bounds__(128) void scan_kernel(
    const int* __restrict__ seq, const float* __restrict__ ws,
    const float* __restrict__ Wrp, const float* __restrict__ brp,
    const float* __restrict__ Wo, const float* __restrict__ bo,
    float* __restrict__ out)
{
    const int b    = blockIdx.x;
    const int tid  = threadIdx.x;        // 0..127
    const int w    = tid >> 6;           // wave: 0 = s-branch, 1 = e-branch
    const int lane = tid & 63;
    const int l7   = lane & 7;
    const bool is_e = (w == 1);

    __shared__ __align__(16) float4 Wt4[9][2][256];   // 72 KB, transposed
    __shared__ __align__(16) int    toklds[SEQLEN];   // 8 KB (prologue only)
    __shared__ float wacc_s[2][64];
    __shared__ float r_s[64];
    __shared__ float t1_s[64];

    const float* Gg = ws + 8192 + w * 4096;
    const int*   sq = seq + b * SEQLEN;

    // ---- stage token sequence (for the W-build prologue) ----
    {
        const int4* sq4 = (const int4*)sq;
        int4* tl = (int4*)toklds;
        #pragma unroll
        for (int i = 0; i < 4; ++i) tl[tid + i * 128] = sq4[tid + i * 128];
    }
    __syncthreads();

    // ---- precompute W packs: lanes parallel over chunks (4 per lane) ----
    {
        const float invL = 1.0f / (float)SEQLEN;
        #pragma unroll
        for (int qq = 0; qq < 4; ++qq) {
            const int c = lane + (qq << 6);
            int tj[8];
            #pragma unroll
            for (int j = 0; j < 8; ++j) tj[j] = toklds[c * 8 + j];
            float Wp[36];
            build_wpack(tj, (float)(8 * c + 1) * invL, invL, is_e, c == 255, Wp, Gg);
            #pragma unroll
            for (int i = 0; i < 9; ++i)
                Wt4[i][w][c] = make_float4(Wp[4*i], Wp[4*i+1], Wp[4*i+2], Wp[4*i+3]);
        }
    }
    __syncthreads();

    // ---- serial backward sweep ----
    Chunk A, B;
    float u, waccv = 0.0f;

    // prologue: chunk 255 fully, chunk 254 lane-tokens
    A.tokv = sq[2040 + l7];                    // VMEM per-lane
    #pragma unroll
    for (int j = 0; j < 8; ++j) A.tk[j] = RLI(A.tokv, j);
    #pragma unroll
    for (int j = 0; j < 8; ++j) A.grow[j] = Gg[A.tk[j] * 64 + lane];
    #pragma unroll
    for (int i = 0; i < 9; ++i) {
        float4 v = Wt4[i][w][255];
        A.W[4*i] = v.x; A.W[4*i+1] = v.y; A.W[4*i+2] = v.z; A.W[4*i+3] = v.w;
    }
    B.tokv = sq[2032 + l7];
    u = Gg[A.tk[7] * 64 + lane];               // query token = position 2047
    float braw = __shfl(u, A.tokv, 64);        // t-raw for chunk 255

    auto body = [&](Chunk& cur, Chunk& nxt, int c) {
        // ---- chain head: consume braw (issued end of previous body) ----
        float t0 = RLF(braw, 0), t1 = RLF(braw, 1), t2 = RLF(braw, 2), t3 = RLF(braw, 3);
        float t4 = RLF(braw, 4), t5 = RLF(braw, 5), t6 = RLF(braw, 6), t7 = RLF(braw, 7);

        // ---- prefetch chunk c-1 into nxt (all off-chain) ----
        const int cm1 = (c > 0) ? c - 1 : 0;
        const int cm2 = (c > 1) ? c - 2 : 0;
        #pragma unroll
        for (int j = 0; j < 8; ++j) nxt.tk[j] = RLI(nxt.tokv, j);
        #pragma unroll
        for (int j = 0; j < 8; ++j) nxt.grow[j] = Gg[nxt.tk[j] * 64 + lane];
        #pragma unroll
        for (int i = 0; i < 9; ++i) {
            float4 v = Wt4[i][w][cm1];
            nxt.W[4*i] = v.x; nxt.W[4*i+1] = v.y; nxt.W[4*i+2] = v.z; nxt.W[4*i+3] = v.w;
        }
        int tokv2 = sq[cm2 * 8 + l7];          // VMEM per-lane (chunk c-2)

        // ---- s = W t  (36 independent FMAs, depth <= 4) ----
        const float* W = cur.W;
        float s7 = W[35] * t7;
        float s6 = fmaf(W[27], t6, W[34] * t7);
        float s5 = fmaf(W[20], t5, W[26] * t6) + W[33] * t7;
        float s4 = fmaf(W[14], t4, W[19] * t5) + fmaf(W[25], t6, W[32] * t7);
        float s3 = fmaf(W[9],  t3, W[13] * t4) + fmaf(W[18], t5, fmaf(W[24], t6, W[31] * t7));
        float s2 = fmaf(W[5],  t2, W[8]  * t3) + fmaf(W[12], t4, W[17] * t5) + fmaf(W[23], t6, W[30] * t7);
        float s1 = fmaf(W[2],  t1, W[4]  * t2) + fmaf(W[7],  t3, W[11] * t4) + fmaf(W[16], t5, fmaf(W[22], t6, W[29] * t7));
        float s0 = fmaf(W[0],  t0, W[1]  * t1) + fmaf(W[3],  t2, W[6]  * t3) + fmaf(W[10], t4, W[15] * t5) + fmaf(W[21], t6, W[28] * t7);

        // ---- u[a] -= sum_j s_j * G[tok_j][a] ----
        float dA = fmaf(cur.grow[0], s0, fmaf(cur.grow[1], s1, fmaf(cur.grow[2], s2, cur.grow[3] * s3)));
        float dB = fmaf(cur.grow[4], s4, fmaf(cur.grow[5], s5, fmaf(cur.grow[6], s6, cur.grow[7] * s7)));
        u -= (dA + dB);

        // ---- issue next braw IMMEDIATELY (full body of slack) ----
        braw = __shfl(u, nxt.tokv, 64);

        // ---- wacc[tok_j] += s_j  (lane = token; off-chain) ----
        waccv += (lane == cur.tk[0]) ? s0 : 0.0f;
        waccv += (lane == cur.tk[1]) ? s1 : 0.0f;
        waccv += (lane == cur.tk[2]) ? s2 : 0.0f;
        waccv += (lane == cur.tk[3]) ? s3 : 0.0f;
        waccv += (lane == cur.tk[4]) ? s4 : 0.0f;
        waccv += (lane == cur.tk[5]) ? s5 : 0.0f;
        waccv += (lane == cur.tk[6]) ? s6 : 0.0f;
        waccv += (lane == cur.tk[7]) ? s7 : 0.0f;

        cur.tokv = tokv2;   // retire cur; becomes chunk c-2's lane tokens
    };

    for (int c = 255; c >= 1; c -= 2) {
        body(A, B, c);
        body(B, A, c - 1);
    }

    wacc_s[w][lane] = waccv;
    __syncthreads();

    // r[w2][rho] = sum_tok wacc[w2][tok] * v[w2][tok][rho]  (v from global ws)
    if (tid < 64) {
        const int w2  = tid >> 5;
        const int rho = tid & 31;
        const float* vv = ws + 4096 + w2 * 2048;
        const float* wa = &wacc_s[w2][0];
        float acc = 0.0f;
        #pragma unroll 8
        for (int tok = 0; tok < 64; ++tok) acc = fmaf(wa[tok], vv[tok * 32 + rho], acc);
        r_s[tid] = acc;
    }
    __syncthreads();

    // out = (r @ Wrp.T + brp) @ Wo.T + bo
    if (tid < 64) {
        float acc = brp[tid];
        #pragma unroll 8
        for (int m = 0; m < 64; ++m) acc = fmaf(Wrp[tid * 64 + m], r_s[m], acc);
        t1_s[tid] = acc;
    }
    __syncthreads();
    if (tid < 64) {
        float acc = bo[tid];
        #pragma unroll 8
        for (int m = 0; m < 64; ++m) acc = fmaf(Wo[tid * 64 + m], t1_s[m], acc);
        out[b * 64 + tid] = acc;
    }
}

extern "C" void kernel_launch(void* const* d_in, const int* in_sizes, int n_in,
                              void* d_out, int out_size, void* d_ws, size_t ws_size,
                              hipStream_t stream)
{
    const int*   seq   = (const int*)  d_in[0];
    const float* embed = (const float*)d_in[1];
    const float* W1    = (const float*)d_in[2];
    const float* b1    = (const float*)d_in[3];
    const float* W2    = (const float*)d_in[4];
    const float* b2    = (const float*)d_in[5];
    const float* ln_g  = (const float*)d_in[6];
    const float* ln_b  = (const float*)d_in[7];
    const float* Ws    = (const float*)d_in[8];
    const float* bs    = (const float*)d_in[9];
    const float* We    = (const float*)d_in[10];
    const float* be    = (const float*)d_in[11];
    const float* Wrp   = (const float*)d_in[12];
    const float* brp   = (const float*)d_in[13];
    const float* Wo    = (const float*)d_in[14];
    const float* bo    = (const float*)d_in[15];
    float* ws  = (float*)d_ws;
    float* out = (float*)d_out;

    hipLaunchKernelGGL(vocab_kernel, dim3(VOCAB), dim3(64), 0, stream,
                       embed, W1, b1, W2, b2, ln_g, ln_b, Ws, bs, We, be, ws);
    hipLaunchKernelGGL(gram_kernel, dim3(2), dim3(256), 0, stream, ws);
    hipLaunchKernelGGL(scan_kernel, dim3(BATCH), dim3(128), 0, stream,
                       seq, ws, Wrp, brp, Wo, bo, out);
}